// Round 6
// baseline (637.167 us; speedup 1.0000x reference)
//
#include <hip/hip_runtime.h>

#define HID 128
#define BM 64         // gemm row tile
#define BK 64         // k-phase: Wsh holds 64 k-rows (32 KB); 2 phases per layer

// ---------------- CSR build ----------------

__global__ __launch_bounds__(256) void k_count(const int* __restrict__ ei, int E,
                                               int* __restrict__ deg) {
    int e = blockIdx.x * 256 + threadIdx.x;
    if (e < E) atomicAdd(&deg[ei[E + e]], 1);   // row 1 of edge_index = dst
}

__global__ __launch_bounds__(256) void k_scan1(const int* __restrict__ deg,
                                               int* __restrict__ rowptr,
                                               int* __restrict__ partial, int n) {
    __shared__ int s[256];
    int tid = threadIdx.x;
    int i = blockIdx.x * 256 + tid;
    int v = (i < n) ? deg[i] : 0;
    s[tid] = v;
    __syncthreads();
    for (int off = 1; off < 256; off <<= 1) {
        int t = (tid >= off) ? s[tid - off] : 0;
        __syncthreads();
        s[tid] += t;
        __syncthreads();
    }
    if (i < n) rowptr[i] = s[tid] - v;           // block-local exclusive
    if (tid == 255) partial[blockIdx.x] = s[255];
}

__global__ __launch_bounds__(256) void k_scan2(int* __restrict__ partial, int nb) {
    __shared__ int s[256];
    int tid = threadIdx.x;
    int v = (tid < nb) ? partial[tid] : 0;
    s[tid] = v;
    __syncthreads();
    for (int off = 1; off < 256; off <<= 1) {
        int t = (tid >= off) ? s[tid - off] : 0;
        __syncthreads();
        s[tid] += t;
        __syncthreads();
    }
    if (tid < nb) partial[tid] = s[tid] - v;     // exclusive over block sums
}

__global__ __launch_bounds__(256) void k_scan3(int* __restrict__ rowptr,
                                               const int* __restrict__ partial,
                                               int n, int E) {
    int i = blockIdx.x * 256 + threadIdx.x;
    if (i < n) rowptr[i] += partial[blockIdx.x];
    if (i == 0) rowptr[n] = E;
}

__global__ __launch_bounds__(256) void k_dis(const int* __restrict__ deg,
                                             float* __restrict__ dis, int n) {
    int i = blockIdx.x * 256 + threadIdx.x;
    if (i < n) dis[i] = 1.0f / sqrtf((float)(deg[i] + 1));  // +1 self-loop
}

__global__ __launch_bounds__(256) void k_fill(const int* __restrict__ ei, int E,
                                              const int* __restrict__ rowptr,
                                              int* __restrict__ cursor,
                                              int* __restrict__ col) {
    int e = blockIdx.x * 256 + threadIdx.x;
    if (e < E) {
        int d = ei[E + e];
        int p = atomicAdd(&cursor[d], 1);
        col[rowptr[d] + p] = ei[e];
    }
}

// ---------------- per-layer kernels ----------------

// T[i,:] = dis[i] * (A[i,:] @ W)
// 256 threads; tile BM=64 x 128; thread tile 8r x 4c.
// BOTH operands in LDS: As (full 128-k, 32 KB) + Wsh (one 64-k phase, 32 KB).
// W is read from L2 exactly ONCE per block (64 KB) — kills the 8x ty-group
// redundancy (400 MB/layer L1/L2 traffic) that limited the register-prefetch
// versions. No padding needed: A reads are half-wave-uniform broadcasts,
// W reads are lane-contiguous — both conflict-free.
__global__ __launch_bounds__(256, 2) void k_gemm(const float* __restrict__ A,
                                                 const float* __restrict__ W,
                                                 const float* __restrict__ dis,
                                                 float* __restrict__ T, int n) {
    __shared__ float As[BM * HID];    // 32 KB
    __shared__ float Wsh[BK * HID];   // 32 KB
    int r0 = blockIdx.x * BM;
    int tid = threadIdx.x;
    int rows = n - r0; if (rows > BM) rows = BM;
    {
        const float4* A4 = (const float4*)(A + (size_t)r0 * HID);
        float4* As4 = (float4*)As;
        int tot = rows * (HID / 4);
        for (int i = tid; i < tot; i += 256) As4[i] = A4[i];
    }

    int tx = tid & 31, ty = tid >> 5;    // 32 col-groups x 8 row-groups
    int rr0 = ty * 8, c0 = tx * 4;

    float acc[8][4];
    #pragma unroll
    for (int r = 0; r < 8; ++r) { acc[r][0]=0.f; acc[r][1]=0.f; acc[r][2]=0.f; acc[r][3]=0.f; }

    #pragma unroll 1
    for (int ph = 0; ph < 2; ++ph) {
        __syncthreads();    // phase 0: covers As staging; phase 1: Wsh readers done
        {
            const float4* Wg = (const float4*)(W + (size_t)ph * BK * HID);
            float4* Ws4 = (float4*)Wsh;
            #pragma unroll
            for (int i = 0; i < 8; ++i) Ws4[tid + i * 256] = Wg[tid + i * 256];
        }
        __syncthreads();

        const float* Asb = As + rr0 * HID + ph * BK;
        #pragma unroll 2
        for (int kq = 0; kq < BK; kq += 4) {
            float4 w0 = *(const float4*)&Wsh[(kq + 0) * HID + c0];
            float4 w1 = *(const float4*)&Wsh[(kq + 1) * HID + c0];
            float4 w2 = *(const float4*)&Wsh[(kq + 2) * HID + c0];
            float4 w3 = *(const float4*)&Wsh[(kq + 3) * HID + c0];
            #pragma unroll
            for (int r = 0; r < 8; ++r) {
                float4 a = *(const float4*)&Asb[r * HID + kq];
                acc[r][0] = fmaf(a.x, w0.x, acc[r][0]);
                acc[r][1] = fmaf(a.x, w0.y, acc[r][1]);
                acc[r][2] = fmaf(a.x, w0.z, acc[r][2]);
                acc[r][3] = fmaf(a.x, w0.w, acc[r][3]);
                acc[r][0] = fmaf(a.y, w1.x, acc[r][0]);
                acc[r][1] = fmaf(a.y, w1.y, acc[r][1]);
                acc[r][2] = fmaf(a.y, w1.z, acc[r][2]);
                acc[r][3] = fmaf(a.y, w1.w, acc[r][3]);
                acc[r][0] = fmaf(a.z, w2.x, acc[r][0]);
                acc[r][1] = fmaf(a.z, w2.y, acc[r][1]);
                acc[r][2] = fmaf(a.z, w2.z, acc[r][2]);
                acc[r][3] = fmaf(a.z, w2.w, acc[r][3]);
                acc[r][0] = fmaf(a.w, w3.x, acc[r][0]);
                acc[r][1] = fmaf(a.w, w3.y, acc[r][1]);
                acc[r][2] = fmaf(a.w, w3.z, acc[r][2]);
                acc[r][3] = fmaf(a.w, w3.w, acc[r][3]);
            }
        }
    }

    int c0o = tx * 4;
    #pragma unroll
    for (int r = 0; r < 8; ++r) {
        int row = rr0 + r;
        if (row < rows) {
            float d = dis[r0 + row];
            float4 o = make_float4(acc[r][0] * d, acc[r][1] * d, acc[r][2] * d, acc[r][3] * d);
            *(float4*)&T[(size_t)(r0 + row) * HID + c0o] = o;
        }
    }
}

// H[i,:] = relu(dis[i] * (T[i,:] + sum_{j in adj(i)} T[j,:]) + b)
// half-wave (32 lanes x float4) per node; cascade unroll 8/2/1 -> 8 gathers in flight.
__global__ __launch_bounds__(256) void k_agg(const float* __restrict__ T,
                                             const int* __restrict__ rowptr,
                                             const int* __restrict__ col,
                                             const float* __restrict__ dis,
                                             const float* __restrict__ b,
                                             float* __restrict__ H, int n) {
    int node = (blockIdx.x * 256 + threadIdx.x) >> 5;
    int lane = threadIdx.x & 31;
    if (node >= n) return;
    size_t foff = (size_t)(lane * 4);
    size_t base = (size_t)node * HID + foff;
    float4 acc = *(const float4*)&T[base];          // self-loop (pre-scaled by dis[j])
    float4 acc2 = make_float4(0.f, 0.f, 0.f, 0.f);
    int e = rowptr[node], e1 = rowptr[node + 1];
    for (; e + 8 <= e1; e += 8) {
        int j0 = col[e + 0];
        int j1 = col[e + 1];
        int j2 = col[e + 2];
        int j3 = col[e + 3];
        int j4 = col[e + 4];
        int j5 = col[e + 5];
        int j6 = col[e + 6];
        int j7 = col[e + 7];
        float4 v0 = *(const float4*)&T[(size_t)j0 * HID + foff];
        float4 v1 = *(const float4*)&T[(size_t)j1 * HID + foff];
        float4 v2 = *(const float4*)&T[(size_t)j2 * HID + foff];
        float4 v3 = *(const float4*)&T[(size_t)j3 * HID + foff];
        float4 v4 = *(const float4*)&T[(size_t)j4 * HID + foff];
        float4 v5 = *(const float4*)&T[(size_t)j5 * HID + foff];
        float4 v6 = *(const float4*)&T[(size_t)j6 * HID + foff];
        float4 v7 = *(const float4*)&T[(size_t)j7 * HID + foff];
        acc.x  += (v0.x + v1.x) + (v2.x + v3.x);
        acc.y  += (v0.y + v1.y) + (v2.y + v3.y);
        acc.z  += (v0.z + v1.z) + (v2.z + v3.z);
        acc.w  += (v0.w + v1.w) + (v2.w + v3.w);
        acc2.x += (v4.x + v5.x) + (v6.x + v7.x);
        acc2.y += (v4.y + v5.y) + (v6.y + v7.y);
        acc2.z += (v4.z + v5.z) + (v6.z + v7.z);
        acc2.w += (v4.w + v5.w) + (v6.w + v7.w);
    }
    for (; e + 2 <= e1; e += 2) {
        int j0 = col[e + 0];
        int j1 = col[e + 1];
        float4 v0 = *(const float4*)&T[(size_t)j0 * HID + foff];
        float4 v1 = *(const float4*)&T[(size_t)j1 * HID + foff];
        acc.x  += v0.x; acc.y  += v0.y; acc.z  += v0.z; acc.w  += v0.w;
        acc2.x += v1.x; acc2.y += v1.y; acc2.z += v1.z; acc2.w += v1.w;
    }
    if (e < e1) {
        int j = col[e];
        float4 v = *(const float4*)&T[(size_t)j * HID + foff];
        acc.x += v.x; acc.y += v.y; acc.z += v.z; acc.w += v.w;
    }
    acc.x += acc2.x; acc.y += acc2.y; acc.z += acc2.z; acc.w += acc2.w;
    float d = dis[node];
    float4 bb = *(const float4*)&b[lane * 4];
    float4 o;
    o.x = fmaxf(fmaf(d, acc.x, bb.x), 0.0f);
    o.y = fmaxf(fmaf(d, acc.y, bb.y), 0.0f);
    o.z = fmaxf(fmaf(d, acc.z, bb.z), 0.0f);
    o.w = fmaxf(fmaf(d, acc.w, bb.w), 0.0f);
    *(float4*)&H[base] = o;
}

// out[i] = H[i,:] @ lin_w + lin_b    half-wave per node
__global__ __launch_bounds__(256) void k_final(const float* __restrict__ H,
                                               const float* __restrict__ w,
                                               const float* __restrict__ lb,
                                               float* __restrict__ out, int n) {
    int node = (blockIdx.x * 256 + threadIdx.x) >> 5;
    int lane = threadIdx.x & 31;
    if (node >= n) return;
    float4 h = *(const float4*)&H[(size_t)node * HID + lane * 4];
    float4 ww = *(const float4*)&w[lane * 4];
    float s = h.x * ww.x + h.y * ww.y + h.z * ww.z + h.w * ww.w;
    #pragma unroll
    for (int o = 16; o > 0; o >>= 1) s += __shfl_down(s, o, 64);  // stays within half
    if (lane == 0) out[node] = s + lb[0];
}

// ---------------- launch ----------------

extern "C" void kernel_launch(void* const* d_in, const int* in_sizes, int n_in,
                              void* d_out, int out_size, void* d_ws, size_t ws_size,
                              hipStream_t stream) {
    const float* x     = (const float*)d_in[0];
    const int*   ei    = (const int*)d_in[1];
    const float* Ws    = (const float*)d_in[2];
    const float* bs    = (const float*)d_in[3];
    const float* lin_w = (const float*)d_in[4];
    const float* lin_b = (const float*)d_in[5];
    float* out = (float*)d_out;

    int n = in_sizes[0] / HID;           // 50000
    int E = in_sizes[1] / 2;             // 600000
    int L = in_sizes[2] / (HID * HID);   // 7

    char* ws = (char*)d_ws;
    size_t off = 0;
    auto alloc = [&](size_t bytes) -> void* {
        void* p = ws + off;
        off += (bytes + 255) & ~(size_t)255;
        return p;
    };
    int*   deg     = (int*)alloc((size_t)n * 4);
    int*   cursor  = (int*)alloc((size_t)n * 4);
    int*   rowptr  = (int*)alloc((size_t)(n + 1) * 4);
    int*   partial = (int*)alloc(1024);
    float* dis     = (float*)alloc((size_t)n * 4);
    int*   col     = (int*)alloc((size_t)E * 4);
    float* hbuf    = (float*)alloc((size_t)n * HID * 4);
    float* tbuf    = (float*)alloc((size_t)n * HID * 4);
    (void)ws_size;

    hipMemsetAsync(deg, 0, (size_t)n * 4, stream);
    hipMemsetAsync(cursor, 0, (size_t)n * 4, stream);

    int eb = (E + 255) / 256;
    int nb = (n + 255) / 256;
    k_count<<<eb, 256, 0, stream>>>(ei, E, deg);
    k_scan1<<<nb, 256, 0, stream>>>(deg, rowptr, partial, n);
    k_scan2<<<1, 256, 0, stream>>>(partial, nb);
    k_scan3<<<nb, 256, 0, stream>>>(rowptr, partial, n, E);
    k_dis<<<nb, 256, 0, stream>>>(deg, dis, n);
    k_fill<<<eb, 256, 0, stream>>>(ei, E, rowptr, cursor, col);

    const float* hin = x;
    int gb = (n + BM - 1) / BM;  // 782 GEMM blocks
    int hb = (n + 7) / 8;        // 8 half-waves (=nodes) per 256-thread block
    for (int l = 0; l < L; ++l) {
        k_gemm<<<gb, 256, 0, stream>>>(hin, Ws + (size_t)l * HID * HID, dis, tbuf, n);
        k_agg<<<hb, 256, 0, stream>>>(tbuf, rowptr, col, dis, bs + (size_t)l * HID, hbuf, n);
        hin = hbuf;
    }
    k_final<<<hb, 256, 0, stream>>>(hbuf, lin_w, lin_b, out, n);
}

// Round 7
// 568.284 us; speedup vs baseline: 1.1212x; 1.1212x over previous
//
#include <hip/hip_runtime.h>

#define HID 128
#define ASPITCH 132   // padded A-tile pitch for k_gemm0 (round-5 proven)
#define BM 64

// ---------------- CSR build ----------------

__global__ __launch_bounds__(256) void k_count(const int* __restrict__ ei, int E,
                                               int* __restrict__ deg) {
    int e = blockIdx.x * 256 + threadIdx.x;
    if (e < E) atomicAdd(&deg[ei[E + e]], 1);   // row 1 of edge_index = dst
}

__global__ __launch_bounds__(256) void k_scan1(const int* __restrict__ deg,
                                               int* __restrict__ rowptr,
                                               int* __restrict__ partial, int n) {
    __shared__ int s[256];
    int tid = threadIdx.x;
    int i = blockIdx.x * 256 + tid;
    int v = (i < n) ? deg[i] : 0;
    s[tid] = v;
    __syncthreads();
    for (int off = 1; off < 256; off <<= 1) {
        int t = (tid >= off) ? s[tid - off] : 0;
        __syncthreads();
        s[tid] += t;
        __syncthreads();
    }
    if (i < n) rowptr[i] = s[tid] - v;           // block-local exclusive
    if (tid == 255) partial[blockIdx.x] = s[255];
}

__global__ __launch_bounds__(256) void k_scan2(int* __restrict__ partial, int nb) {
    __shared__ int s[256];
    int tid = threadIdx.x;
    int v = (tid < nb) ? partial[tid] : 0;
    s[tid] = v;
    __syncthreads();
    for (int off = 1; off < 256; off <<= 1) {
        int t = (tid >= off) ? s[tid - off] : 0;
        __syncthreads();
        s[tid] += t;
        __syncthreads();
    }
    if (tid < nb) partial[tid] = s[tid] - v;     // exclusive over block sums
}

__global__ __launch_bounds__(256) void k_scan3(int* __restrict__ rowptr,
                                               const int* __restrict__ partial,
                                               int n, int E) {
    int i = blockIdx.x * 256 + threadIdx.x;
    if (i < n) rowptr[i] += partial[blockIdx.x];
    if (i == 0) rowptr[n] = E;
}

__global__ __launch_bounds__(256) void k_dis(const int* __restrict__ deg,
                                             float* __restrict__ dis, int n) {
    int i = blockIdx.x * 256 + threadIdx.x;
    if (i < n) dis[i] = 1.0f / sqrtf((float)(deg[i] + 1));  // +1 self-loop
}

__global__ __launch_bounds__(256) void k_fill(const int* __restrict__ ei, int E,
                                              const int* __restrict__ rowptr,
                                              int* __restrict__ cursor,
                                              int* __restrict__ col) {
    int e = blockIdx.x * 256 + threadIdx.x;
    if (e < E) {
        int d = ei[E + e];
        int p = atomicAdd(&cursor[d], 1);
        col[rowptr[d] + p] = ei[e];
    }
}

// ---------------- compute kernels ----------------

// U[i,:] = dis[i] * (A[i,:] @ W)   — first-layer GEMM (round-5 version, proven).
__global__ __launch_bounds__(256, 3) void k_gemm0(const float* __restrict__ A,
                                                  const float* __restrict__ W,
                                                  const float* __restrict__ dis,
                                                  float* __restrict__ T, int n) {
    __shared__ float As[BM * ASPITCH];
    int r0 = blockIdx.x * BM;
    int tid = threadIdx.x;
    int rows = n - r0; if (rows > BM) rows = BM;
    {
        const float4* A4 = (const float4*)(A + (size_t)r0 * HID);
        int tot = rows * (HID / 4);
        for (int i = tid; i < tot; i += 256) {
            int row = i >> 5, c = (i & 31) << 2;
            *(float4*)&As[row * ASPITCH + c] = A4[i];
        }
    }
    __syncthreads();

    int tx = tid & 31, ty = tid >> 5;
    int rr0 = ty * 8;
    const float4* W4 = (const float4*)W;

    float acc[8][4];
    #pragma unroll
    for (int r = 0; r < 8; ++r) { acc[r][0]=0.f; acc[r][1]=0.f; acc[r][2]=0.f; acc[r][3]=0.f; }

    float4 wa0 = W4[0 * 32 + tx];
    float4 wa1 = W4[1 * 32 + tx];
    float4 wa2 = W4[2 * 32 + tx];
    float4 wa3 = W4[3 * 32 + tx];
    float4 wb0, wb1, wb2, wb3;

    #pragma unroll 1
    for (int k = 0; k < HID; k += 8) {
        wb0 = W4[(k + 4) * 32 + tx];
        wb1 = W4[(k + 5) * 32 + tx];
        wb2 = W4[(k + 6) * 32 + tx];
        wb3 = W4[(k + 7) * 32 + tx];
        #pragma unroll
        for (int r = 0; r < 8; ++r) {
            float4 a = *(const float4*)&As[(rr0 + r) * ASPITCH + k];
            acc[r][0] = fmaf(a.x, wa0.x, acc[r][0]);
            acc[r][1] = fmaf(a.x, wa0.y, acc[r][1]);
            acc[r][2] = fmaf(a.x, wa0.z, acc[r][2]);
            acc[r][3] = fmaf(a.x, wa0.w, acc[r][3]);
            acc[r][0] = fmaf(a.y, wa1.x, acc[r][0]);
            acc[r][1] = fmaf(a.y, wa1.y, acc[r][1]);
            acc[r][2] = fmaf(a.y, wa1.z, acc[r][2]);
            acc[r][3] = fmaf(a.y, wa1.w, acc[r][3]);
            acc[r][0] = fmaf(a.z, wa2.x, acc[r][0]);
            acc[r][1] = fmaf(a.z, wa2.y, acc[r][1]);
            acc[r][2] = fmaf(a.z, wa2.z, acc[r][2]);
            acc[r][3] = fmaf(a.z, wa2.w, acc[r][3]);
            acc[r][0] = fmaf(a.w, wa3.x, acc[r][0]);
            acc[r][1] = fmaf(a.w, wa3.y, acc[r][1]);
            acc[r][2] = fmaf(a.w, wa3.z, acc[r][2]);
            acc[r][3] = fmaf(a.w, wa3.w, acc[r][3]);
        }
        if (k + 8 < HID) {
            wa0 = W4[(k + 8)  * 32 + tx];
            wa1 = W4[(k + 9)  * 32 + tx];
            wa2 = W4[(k + 10) * 32 + tx];
            wa3 = W4[(k + 11) * 32 + tx];
        }
        #pragma unroll
        for (int r = 0; r < 8; ++r) {
            float4 a = *(const float4*)&As[(rr0 + r) * ASPITCH + k + 4];
            acc[r][0] = fmaf(a.x, wb0.x, acc[r][0]);
            acc[r][1] = fmaf(a.x, wb0.y, acc[r][1]);
            acc[r][2] = fmaf(a.x, wb0.z, acc[r][2]);
            acc[r][3] = fmaf(a.x, wb0.w, acc[r][3]);
            acc[r][0] = fmaf(a.y, wb1.x, acc[r][0]);
            acc[r][1] = fmaf(a.y, wb1.y, acc[r][1]);
            acc[r][2] = fmaf(a.y, wb1.z, acc[r][2]);
            acc[r][3] = fmaf(a.y, wb1.w, acc[r][3]);
            acc[r][0] = fmaf(a.z, wb2.x, acc[r][0]);
            acc[r][1] = fmaf(a.z, wb2.y, acc[r][1]);
            acc[r][2] = fmaf(a.z, wb2.z, acc[r][2]);
            acc[r][3] = fmaf(a.z, wb2.w, acc[r][3]);
            acc[r][0] = fmaf(a.w, wb3.x, acc[r][0]);
            acc[r][1] = fmaf(a.w, wb3.y, acc[r][1]);
            acc[r][2] = fmaf(a.w, wb3.z, acc[r][2]);
            acc[r][3] = fmaf(a.w, wb3.w, acc[r][3]);
        }
    }

    int c0 = tx * 4;
    #pragma unroll
    for (int r = 0; r < 8; ++r) {
        int row = rr0 + r;
        if (row < rows) {
            float d = dis[r0 + row];
            float4 o = make_float4(acc[r][0] * d, acc[r][1] * d, acc[r][2] * d, acc[r][3] * d);
            *(float4*)&T[(size_t)(r0 + row) * HID + c0] = o;
        }
    }
}

// Fused: for a 64-row dst tile,
//   phase A: H[i,:] = relu(dis[i]*(Uin[i,:] + sum_j Uin[j,:]) + b) -> S in LDS
//   phase B: Uout[i,:] = dis[i] * (S[i,:] @ W)      (next layer's pre-scaled input)
// Phase A is gather-latency-bound (VALU idle), phase B is FMA-bound; resident
// blocks on a CU sit in different phases so the pipes overlap (m114 effect).
__global__ __launch_bounds__(256, 3) void k_aggemm(const float* __restrict__ Uin,
                                                   const float* __restrict__ W,
                                                   const float* __restrict__ b,
                                                   const float* __restrict__ dis,
                                                   const int* __restrict__ rowptr,
                                                   const int* __restrict__ col,
                                                   float* __restrict__ Uout, int n) {
    __shared__ float S[BM * HID];   // 32 KB
    int r0 = blockIdx.x * BM;
    int tid = threadIdx.x;
    int hw = tid >> 5, lane = tid & 31;
    size_t foff = (size_t)(lane * 4);
    float4 bb = *(const float4*)&b[lane * 4];

    // ---- phase A: aggregate 8 rows per half-wave ----
    #pragma unroll 1
    for (int rr = 0; rr < 8; ++rr) {
        int row = r0 + hw * 8 + rr;
        float4 acc = make_float4(0.f, 0.f, 0.f, 0.f);
        if (row < n) {
            acc = *(const float4*)&Uin[(size_t)row * HID + foff];   // self (pre-scaled)
            float4 acc2 = make_float4(0.f, 0.f, 0.f, 0.f);
            int e = rowptr[row], e1 = rowptr[row + 1];
            for (; e + 8 <= e1; e += 8) {
                int j0 = col[e + 0];
                int j1 = col[e + 1];
                int j2 = col[e + 2];
                int j3 = col[e + 3];
                int j4 = col[e + 4];
                int j5 = col[e + 5];
                int j6 = col[e + 6];
                int j7 = col[e + 7];
                float4 v0 = *(const float4*)&Uin[(size_t)j0 * HID + foff];
                float4 v1 = *(const float4*)&Uin[(size_t)j1 * HID + foff];
                float4 v2 = *(const float4*)&Uin[(size_t)j2 * HID + foff];
                float4 v3 = *(const float4*)&Uin[(size_t)j3 * HID + foff];
                float4 v4 = *(const float4*)&Uin[(size_t)j4 * HID + foff];
                float4 v5 = *(const float4*)&Uin[(size_t)j5 * HID + foff];
                float4 v6 = *(const float4*)&Uin[(size_t)j6 * HID + foff];
                float4 v7 = *(const float4*)&Uin[(size_t)j7 * HID + foff];
                acc.x  += (v0.x + v1.x) + (v2.x + v3.x);
                acc.y  += (v0.y + v1.y) + (v2.y + v3.y);
                acc.z  += (v0.z + v1.z) + (v2.z + v3.z);
                acc.w  += (v0.w + v1.w) + (v2.w + v3.w);
                acc2.x += (v4.x + v5.x) + (v6.x + v7.x);
                acc2.y += (v4.y + v5.y) + (v6.y + v7.y);
                acc2.z += (v4.z + v5.z) + (v6.z + v7.z);
                acc2.w += (v4.w + v5.w) + (v6.w + v7.w);
            }
            for (; e + 2 <= e1; e += 2) {
                int j0 = col[e + 0];
                int j1 = col[e + 1];
                float4 v0 = *(const float4*)&Uin[(size_t)j0 * HID + foff];
                float4 v1 = *(const float4*)&Uin[(size_t)j1 * HID + foff];
                acc.x  += v0.x; acc.y  += v0.y; acc.z  += v0.z; acc.w  += v0.w;
                acc2.x += v1.x; acc2.y += v1.y; acc2.z += v1.z; acc2.w += v1.w;
            }
            if (e < e1) {
                int j = col[e];
                float4 v = *(const float4*)&Uin[(size_t)j * HID + foff];
                acc.x += v.x; acc.y += v.y; acc.z += v.z; acc.w += v.w;
            }
            float d = dis[row];
            acc.x = fmaxf(fmaf(d, acc.x + acc2.x, bb.x), 0.0f);
            acc.y = fmaxf(fmaf(d, acc.y + acc2.y, bb.y), 0.0f);
            acc.z = fmaxf(fmaf(d, acc.z + acc2.z, bb.z), 0.0f);
            acc.w = fmaxf(fmaf(d, acc.w + acc2.w, bb.w), 0.0f);
        }
        *(float4*)&S[(hw * 8 + rr) * HID + lane * 4] = acc;
    }
    __syncthreads();

    // ---- phase B: S @ W with register ping-pong W prefetch (round-5 body) ----
    int tx = tid & 31, ty = tid >> 5;
    int rr0 = ty * 8;
    const float4* W4 = (const float4*)W;

    float acc[8][4];
    #pragma unroll
    for (int r = 0; r < 8; ++r) { acc[r][0]=0.f; acc[r][1]=0.f; acc[r][2]=0.f; acc[r][3]=0.f; }

    float4 wa0 = W4[0 * 32 + tx];
    float4 wa1 = W4[1 * 32 + tx];
    float4 wa2 = W4[2 * 32 + tx];
    float4 wa3 = W4[3 * 32 + tx];
    float4 wb0, wb1, wb2, wb3;

    #pragma unroll 1
    for (int k = 0; k < HID; k += 8) {
        wb0 = W4[(k + 4) * 32 + tx];
        wb1 = W4[(k + 5) * 32 + tx];
        wb2 = W4[(k + 6) * 32 + tx];
        wb3 = W4[(k + 7) * 32 + tx];
        #pragma unroll
        for (int r = 0; r < 8; ++r) {
            float4 a = *(const float4*)&S[(rr0 + r) * HID + k];
            acc[r][0] = fmaf(a.x, wa0.x, acc[r][0]);
            acc[r][1] = fmaf(a.x, wa0.y, acc[r][1]);
            acc[r][2] = fmaf(a.x, wa0.z, acc[r][2]);
            acc[r][3] = fmaf(a.x, wa0.w, acc[r][3]);
            acc[r][0] = fmaf(a.y, wa1.x, acc[r][0]);
            acc[r][1] = fmaf(a.y, wa1.y, acc[r][1]);
            acc[r][2] = fmaf(a.y, wa1.z, acc[r][2]);
            acc[r][3] = fmaf(a.y, wa1.w, acc[r][3]);
            acc[r][0] = fmaf(a.z, wa2.x, acc[r][0]);
            acc[r][1] = fmaf(a.z, wa2.y, acc[r][1]);
            acc[r][2] = fmaf(a.z, wa2.z, acc[r][2]);
            acc[r][3] = fmaf(a.z, wa2.w, acc[r][3]);
            acc[r][0] = fmaf(a.w, wa3.x, acc[r][0]);
            acc[r][1] = fmaf(a.w, wa3.y, acc[r][1]);
            acc[r][2] = fmaf(a.w, wa3.z, acc[r][2]);
            acc[r][3] = fmaf(a.w, wa3.w, acc[r][3]);
        }
        if (k + 8 < HID) {
            wa0 = W4[(k + 8)  * 32 + tx];
            wa1 = W4[(k + 9)  * 32 + tx];
            wa2 = W4[(k + 10) * 32 + tx];
            wa3 = W4[(k + 11) * 32 + tx];
        }
        #pragma unroll
        for (int r = 0; r < 8; ++r) {
            float4 a = *(const float4*)&S[(rr0 + r) * HID + k + 4];
            acc[r][0] = fmaf(a.x, wb0.x, acc[r][0]);
            acc[r][1] = fmaf(a.x, wb0.y, acc[r][1]);
            acc[r][2] = fmaf(a.x, wb0.z, acc[r][2]);
            acc[r][3] = fmaf(a.x, wb0.w, acc[r][3]);
            acc[r][0] = fmaf(a.y, wb1.x, acc[r][0]);
            acc[r][1] = fmaf(a.y, wb1.y, acc[r][1]);
            acc[r][2] = fmaf(a.y, wb1.z, acc[r][2]);
            acc[r][3] = fmaf(a.y, wb1.w, acc[r][3]);
            acc[r][0] = fmaf(a.z, wb2.x, acc[r][0]);
            acc[r][1] = fmaf(a.z, wb2.y, acc[r][1]);
            acc[r][2] = fmaf(a.z, wb2.z, acc[r][2]);
            acc[r][3] = fmaf(a.z, wb2.w, acc[r][3]);
            acc[r][0] = fmaf(a.w, wb3.x, acc[r][0]);
            acc[r][1] = fmaf(a.w, wb3.y, acc[r][1]);
            acc[r][2] = fmaf(a.w, wb3.z, acc[r][2]);
            acc[r][3] = fmaf(a.w, wb3.w, acc[r][3]);
        }
    }

    int rows = n - r0; if (rows > BM) rows = BM;
    int c0 = tx * 4;
    #pragma unroll
    for (int r = 0; r < 8; ++r) {
        int row = rr0 + r;
        if (row < rows) {
            float d = dis[r0 + row];
            float4 o = make_float4(acc[r][0] * d, acc[r][1] * d, acc[r][2] * d, acc[r][3] * d);
            *(float4*)&Uout[(size_t)(r0 + row) * HID + c0] = o;
        }
    }
}

// Last layer: aggregate + bias + relu + dot with lin_w, all in registers.
// half-wave per node.
__global__ __launch_bounds__(256) void k_agglin(const float* __restrict__ Uin,
                                                const float* __restrict__ b,
                                                const float* __restrict__ dis,
                                                const int* __restrict__ rowptr,
                                                const int* __restrict__ col,
                                                const float* __restrict__ lw,
                                                const float* __restrict__ lb,
                                                float* __restrict__ out, int n) {
    int node = (blockIdx.x * 256 + threadIdx.x) >> 5;
    int lane = threadIdx.x & 31;
    if (node >= n) return;
    size_t foff = (size_t)(lane * 4);
    float4 acc = *(const float4*)&Uin[(size_t)node * HID + foff];
    float4 acc2 = make_float4(0.f, 0.f, 0.f, 0.f);
    int e = rowptr[node], e1 = rowptr[node + 1];
    for (; e + 8 <= e1; e += 8) {
        int j0 = col[e + 0];
        int j1 = col[e + 1];
        int j2 = col[e + 2];
        int j3 = col[e + 3];
        int j4 = col[e + 4];
        int j5 = col[e + 5];
        int j6 = col[e + 6];
        int j7 = col[e + 7];
        float4 v0 = *(const float4*)&Uin[(size_t)j0 * HID + foff];
        float4 v1 = *(const float4*)&Uin[(size_t)j1 * HID + foff];
        float4 v2 = *(const float4*)&Uin[(size_t)j2 * HID + foff];
        float4 v3 = *(const float4*)&Uin[(size_t)j3 * HID + foff];
        float4 v4 = *(const float4*)&Uin[(size_t)j4 * HID + foff];
        float4 v5 = *(const float4*)&Uin[(size_t)j5 * HID + foff];
        float4 v6 = *(const float4*)&Uin[(size_t)j6 * HID + foff];
        float4 v7 = *(const float4*)&Uin[(size_t)j7 * HID + foff];
        acc.x  += (v0.x + v1.x) + (v2.x + v3.x);
        acc.y  += (v0.y + v1.y) + (v2.y + v3.y);
        acc.z  += (v0.z + v1.z) + (v2.z + v3.z);
        acc.w  += (v0.w + v1.w) + (v2.w + v3.w);
        acc2.x += (v4.x + v5.x) + (v6.x + v7.x);
        acc2.y += (v4.y + v5.y) + (v6.y + v7.y);
        acc2.z += (v4.z + v5.z) + (v6.z + v7.z);
        acc2.w += (v4.w + v5.w) + (v6.w + v7.w);
    }
    for (; e + 2 <= e1; e += 2) {
        int j0 = col[e + 0];
        int j1 = col[e + 1];
        float4 v0 = *(const float4*)&Uin[(size_t)j0 * HID + foff];
        float4 v1 = *(const float4*)&Uin[(size_t)j1 * HID + foff];
        acc.x  += v0.x; acc.y  += v0.y; acc.z  += v0.z; acc.w  += v0.w;
        acc2.x += v1.x; acc2.y += v1.y; acc2.z += v1.z; acc2.w += v1.w;
    }
    if (e < e1) {
        int j = col[e];
        float4 v = *(const float4*)&Uin[(size_t)j * HID + foff];
        acc.x += v.x; acc.y += v.y; acc.z += v.z; acc.w += v.w;
    }
    float d = dis[node];
    float4 bb = *(const float4*)&b[lane * 4];
    float4 h;
    h.x = fmaxf(fmaf(d, acc.x + acc2.x, bb.x), 0.0f);
    h.y = fmaxf(fmaf(d, acc.y + acc2.y, bb.y), 0.0f);
    h.z = fmaxf(fmaf(d, acc.z + acc2.z, bb.z), 0.0f);
    h.w = fmaxf(fmaf(d, acc.w + acc2.w, bb.w), 0.0f);
    float4 ww = *(const float4*)&lw[lane * 4];
    float s = h.x * ww.x + h.y * ww.y + h.z * ww.z + h.w * ww.w;
    #pragma unroll
    for (int o = 16; o > 0; o >>= 1) s += __shfl_down(s, o, 64);  // stays within half
    if (lane == 0) out[node] = s + lb[0];
}

// ---------------- launch ----------------

extern "C" void kernel_launch(void* const* d_in, const int* in_sizes, int n_in,
                              void* d_out, int out_size, void* d_ws, size_t ws_size,
                              hipStream_t stream) {
    const float* x     = (const float*)d_in[0];
    const int*   ei    = (const int*)d_in[1];
    const float* Ws    = (const float*)d_in[2];
    const float* bs    = (const float*)d_in[3];
    const float* lin_w = (const float*)d_in[4];
    const float* lin_b = (const float*)d_in[5];
    float* out = (float*)d_out;

    int n = in_sizes[0] / HID;           // 50000
    int E = in_sizes[1] / 2;             // 600000
    int L = in_sizes[2] / (HID * HID);   // 7

    char* ws = (char*)d_ws;
    size_t off = 0;
    auto alloc = [&](size_t bytes) -> void* {
        void* p = ws + off;
        off += (bytes + 255) & ~(size_t)255;
        return p;
    };
    int*   deg     = (int*)alloc((size_t)n * 4);
    int*   cursor  = (int*)alloc((size_t)n * 4);
    int*   rowptr  = (int*)alloc((size_t)(n + 1) * 4);
    int*   partial = (int*)alloc(1024);
    float* dis     = (float*)alloc((size_t)n * 4);
    int*   col     = (int*)alloc((size_t)E * 4);
    float* ubuf0   = (float*)alloc((size_t)n * HID * 4);
    float* ubuf1   = (float*)alloc((size_t)n * HID * 4);
    (void)ws_size;

    hipMemsetAsync(deg, 0, (size_t)n * 4, stream);
    hipMemsetAsync(cursor, 0, (size_t)n * 4, stream);

    int eb = (E + 255) / 256;
    int nb = (n + 255) / 256;
    k_count<<<eb, 256, 0, stream>>>(ei, E, deg);
    k_scan1<<<nb, 256, 0, stream>>>(deg, rowptr, partial, n);
    k_scan2<<<1, 256, 0, stream>>>(partial, nb);
    k_scan3<<<nb, 256, 0, stream>>>(rowptr, partial, n, E);
    k_dis<<<nb, 256, 0, stream>>>(deg, dis, n);
    k_fill<<<eb, 256, 0, stream>>>(ei, E, rowptr, cursor, col);

    int gb = (n + BM - 1) / BM;  // 782
    int hb = (n + 7) / 8;

    // U_0 = dis * (x @ W0)
    k_gemm0<<<gb, 256, 0, stream>>>(x, Ws, dis, ubuf0, n);

    // U_{i+1} = dis * (relu(dis*agg(U_i) + b_i) @ W_{i+1})   for i = 0..L-2
    float* uin = ubuf0;
    float* uout = ubuf1;
    for (int i = 0; i + 1 < L; ++i) {
        k_aggemm<<<gb, 256, 0, stream>>>(uin, Ws + (size_t)(i + 1) * HID * HID,
                                         bs + (size_t)i * HID, dis, rowptr, col,
                                         uout, n);
        float* t = uin; uin = uout; uout = t;
    }

    // out = relu(dis*agg(U_{L-1}) + b_{L-1}) @ lin_w + lin_b
    k_agglin<<<hb, 256, 0, stream>>>(uin, bs + (size_t)(L - 1) * HID, dis,
                                     rowptr, col, lin_w, lin_b, out, n);
}

// Round 8
// 566.238 us; speedup vs baseline: 1.1253x; 1.0036x over previous
//
#include <hip/hip_runtime.h>

#define HID 128
#define ASPITCH 132   // padded A-tile pitch for k_gemm0 (round-5 proven)
#define BM 64

// ---------------- CSR build ----------------

__global__ __launch_bounds__(256) void k_count(const int* __restrict__ ei, int E,
                                               int* __restrict__ deg) {
    int e = blockIdx.x * 256 + threadIdx.x;
    if (e < E) atomicAdd(&deg[ei[E + e]], 1);   // row 1 of edge_index = dst
}

__global__ __launch_bounds__(256) void k_scan1(const int* __restrict__ deg,
                                               int* __restrict__ rowptr,
                                               int* __restrict__ partial, int n) {
    __shared__ int s[256];
    int tid = threadIdx.x;
    int i = blockIdx.x * 256 + tid;
    int v = (i < n) ? deg[i] : 0;
    s[tid] = v;
    __syncthreads();
    for (int off = 1; off < 256; off <<= 1) {
        int t = (tid >= off) ? s[tid - off] : 0;
        __syncthreads();
        s[tid] += t;
        __syncthreads();
    }
    if (i < n) rowptr[i] = s[tid] - v;           // block-local exclusive
    if (tid == 255) partial[blockIdx.x] = s[255];
}

__global__ __launch_bounds__(256) void k_scan2(int* __restrict__ partial, int nb) {
    __shared__ int s[256];
    int tid = threadIdx.x;
    int v = (tid < nb) ? partial[tid] : 0;
    s[tid] = v;
    __syncthreads();
    for (int off = 1; off < 256; off <<= 1) {
        int t = (tid >= off) ? s[tid - off] : 0;
        __syncthreads();
        s[tid] += t;
        __syncthreads();
    }
    if (tid < nb) partial[tid] = s[tid] - v;     // exclusive over block sums
}

__global__ __launch_bounds__(256) void k_scan3(int* __restrict__ rowptr,
                                               const int* __restrict__ partial,
                                               int n, int E) {
    int i = blockIdx.x * 256 + threadIdx.x;
    if (i < n) rowptr[i] += partial[blockIdx.x];
    if (i == 0) rowptr[n] = E;
}

__global__ __launch_bounds__(256) void k_dis(const int* __restrict__ deg,
                                             float* __restrict__ dis, int n) {
    int i = blockIdx.x * 256 + threadIdx.x;
    if (i < n) dis[i] = 1.0f / sqrtf((float)(deg[i] + 1));  // +1 self-loop
}

__global__ __launch_bounds__(256) void k_fill(const int* __restrict__ ei, int E,
                                              const int* __restrict__ rowptr,
                                              int* __restrict__ cursor,
                                              int* __restrict__ col) {
    int e = blockIdx.x * 256 + threadIdx.x;
    if (e < E) {
        int d = ei[E + e];
        int p = atomicAdd(&cursor[d], 1);
        col[rowptr[d] + p] = ei[e];
    }
}

// ---------------- compute kernels ----------------

// U[i,:] = dis[i] * (A[i,:] @ W)   — first-layer GEMM (round-5 version, proven).
__global__ __launch_bounds__(256, 3) void k_gemm0(const float* __restrict__ A,
                                                  const float* __restrict__ W,
                                                  const float* __restrict__ dis,
                                                  float* __restrict__ T, int n) {
    __shared__ float As[BM * ASPITCH];
    int r0 = blockIdx.x * BM;
    int tid = threadIdx.x;
    int rows = n - r0; if (rows > BM) rows = BM;
    {
        const float4* A4 = (const float4*)(A + (size_t)r0 * HID);
        int tot = rows * (HID / 4);
        for (int i = tid; i < tot; i += 256) {
            int row = i >> 5, c = (i & 31) << 2;
            *(float4*)&As[row * ASPITCH + c] = A4[i];
        }
    }
    __syncthreads();

    int tx = tid & 31, ty = tid >> 5;
    int rr0 = ty * 8;
    const float4* W4 = (const float4*)W;

    float acc[8][4];
    #pragma unroll
    for (int r = 0; r < 8; ++r) { acc[r][0]=0.f; acc[r][1]=0.f; acc[r][2]=0.f; acc[r][3]=0.f; }

    float4 wa0 = W4[0 * 32 + tx];
    float4 wa1 = W4[1 * 32 + tx];
    float4 wa2 = W4[2 * 32 + tx];
    float4 wa3 = W4[3 * 32 + tx];
    float4 wb0, wb1, wb2, wb3;

    #pragma unroll 1
    for (int k = 0; k < HID; k += 8) {
        wb0 = W4[(k + 4) * 32 + tx];
        wb1 = W4[(k + 5) * 32 + tx];
        wb2 = W4[(k + 6) * 32 + tx];
        wb3 = W4[(k + 7) * 32 + tx];
        #pragma unroll
        for (int r = 0; r < 8; ++r) {
            float4 a = *(const float4*)&As[(rr0 + r) * ASPITCH + k];
            acc[r][0] = fmaf(a.x, wa0.x, acc[r][0]);
            acc[r][1] = fmaf(a.x, wa0.y, acc[r][1]);
            acc[r][2] = fmaf(a.x, wa0.z, acc[r][2]);
            acc[r][3] = fmaf(a.x, wa0.w, acc[r][3]);
            acc[r][0] = fmaf(a.y, wa1.x, acc[r][0]);
            acc[r][1] = fmaf(a.y, wa1.y, acc[r][1]);
            acc[r][2] = fmaf(a.y, wa1.z, acc[r][2]);
            acc[r][3] = fmaf(a.y, wa1.w, acc[r][3]);
            acc[r][0] = fmaf(a.z, wa2.x, acc[r][0]);
            acc[r][1] = fmaf(a.z, wa2.y, acc[r][1]);
            acc[r][2] = fmaf(a.z, wa2.z, acc[r][2]);
            acc[r][3] = fmaf(a.z, wa2.w, acc[r][3]);
            acc[r][0] = fmaf(a.w, wa3.x, acc[r][0]);
            acc[r][1] = fmaf(a.w, wa3.y, acc[r][1]);
            acc[r][2] = fmaf(a.w, wa3.z, acc[r][2]);
            acc[r][3] = fmaf(a.w, wa3.w, acc[r][3]);
        }
        if (k + 8 < HID) {
            wa0 = W4[(k + 8)  * 32 + tx];
            wa1 = W4[(k + 9)  * 32 + tx];
            wa2 = W4[(k + 10) * 32 + tx];
            wa3 = W4[(k + 11) * 32 + tx];
        }
        #pragma unroll
        for (int r = 0; r < 8; ++r) {
            float4 a = *(const float4*)&As[(rr0 + r) * ASPITCH + k + 4];
            acc[r][0] = fmaf(a.x, wb0.x, acc[r][0]);
            acc[r][1] = fmaf(a.x, wb0.y, acc[r][1]);
            acc[r][2] = fmaf(a.x, wb0.z, acc[r][2]);
            acc[r][3] = fmaf(a.x, wb0.w, acc[r][3]);
            acc[r][0] = fmaf(a.y, wb1.x, acc[r][0]);
            acc[r][1] = fmaf(a.y, wb1.y, acc[r][1]);
            acc[r][2] = fmaf(a.y, wb1.z, acc[r][2]);
            acc[r][3] = fmaf(a.y, wb1.w, acc[r][3]);
            acc[r][0] = fmaf(a.z, wb2.x, acc[r][0]);
            acc[r][1] = fmaf(a.z, wb2.y, acc[r][1]);
            acc[r][2] = fmaf(a.z, wb2.z, acc[r][2]);
            acc[r][3] = fmaf(a.z, wb2.w, acc[r][3]);
            acc[r][0] = fmaf(a.w, wb3.x, acc[r][0]);
            acc[r][1] = fmaf(a.w, wb3.y, acc[r][1]);
            acc[r][2] = fmaf(a.w, wb3.z, acc[r][2]);
            acc[r][3] = fmaf(a.w, wb3.w, acc[r][3]);
        }
    }

    int c0 = tx * 4;
    #pragma unroll
    for (int r = 0; r < 8; ++r) {
        int row = rr0 + r;
        if (row < rows) {
            float d = dis[r0 + row];
            float4 o = make_float4(acc[r][0] * d, acc[r][1] * d, acc[r][2] * d, acc[r][3] * d);
            *(float4*)&T[(size_t)(r0 + row) * HID + c0] = o;
        }
    }
}

// Fused: for a 64-row dst tile,
//   phase A: H[i,:] = relu(dis[i]*(Uin[i,:] + sum_j Uin[j,:]) + b) -> S in LDS
//   phase B: Uout[i,:] = dis[i] * (S[i,:] @ W)
// NO BARRIER between phases: S rows ty*8..ty*8+7 are written AND read by the
// same half-wave (hw == ty), so the data flow is half-wave-private; the wave's
// own lgkmcnt orders ds_write -> ds_read. Half-wave pipelines drift apart
// (variable edge counts), so each CU carries a mix of gather-phase (VMEM
// latency) and FMA-phase (VALU) waves — the overlap r7's barrier prevented.
__global__ __launch_bounds__(256, 3) void k_aggemm(const float* __restrict__ Uin,
                                                   const float* __restrict__ W,
                                                   const float* __restrict__ b,
                                                   const float* __restrict__ dis,
                                                   const int* __restrict__ rowptr,
                                                   const int* __restrict__ col,
                                                   float* __restrict__ Uout, int n) {
    __shared__ float S[BM * HID];   // 32 KB
    int r0 = blockIdx.x * BM;
    int tid = threadIdx.x;
    int hw = tid >> 5, lane = tid & 31;
    size_t foff = (size_t)(lane * 4);
    float4 bb = *(const float4*)&b[lane * 4];

    // ---- phase A: aggregate 8 rows per half-wave ----
    #pragma unroll 1
    for (int rr = 0; rr < 8; ++rr) {
        int row = r0 + hw * 8 + rr;
        float4 acc = make_float4(0.f, 0.f, 0.f, 0.f);
        if (row < n) {
            acc = *(const float4*)&Uin[(size_t)row * HID + foff];   // self (pre-scaled)
            float4 acc2 = make_float4(0.f, 0.f, 0.f, 0.f);
            int e = rowptr[row], e1 = rowptr[row + 1];
            for (; e + 8 <= e1; e += 8) {
                int j0 = col[e + 0];
                int j1 = col[e + 1];
                int j2 = col[e + 2];
                int j3 = col[e + 3];
                int j4 = col[e + 4];
                int j5 = col[e + 5];
                int j6 = col[e + 6];
                int j7 = col[e + 7];
                float4 v0 = *(const float4*)&Uin[(size_t)j0 * HID + foff];
                float4 v1 = *(const float4*)&Uin[(size_t)j1 * HID + foff];
                float4 v2 = *(const float4*)&Uin[(size_t)j2 * HID + foff];
                float4 v3 = *(const float4*)&Uin[(size_t)j3 * HID + foff];
                float4 v4 = *(const float4*)&Uin[(size_t)j4 * HID + foff];
                float4 v5 = *(const float4*)&Uin[(size_t)j5 * HID + foff];
                float4 v6 = *(const float4*)&Uin[(size_t)j6 * HID + foff];
                float4 v7 = *(const float4*)&Uin[(size_t)j7 * HID + foff];
                acc.x  += (v0.x + v1.x) + (v2.x + v3.x);
                acc.y  += (v0.y + v1.y) + (v2.y + v3.y);
                acc.z  += (v0.z + v1.z) + (v2.z + v3.z);
                acc.w  += (v0.w + v1.w) + (v2.w + v3.w);
                acc2.x += (v4.x + v5.x) + (v6.x + v7.x);
                acc2.y += (v4.y + v5.y) + (v6.y + v7.y);
                acc2.z += (v4.z + v5.z) + (v6.z + v7.z);
                acc2.w += (v4.w + v5.w) + (v6.w + v7.w);
            }
            for (; e + 2 <= e1; e += 2) {
                int j0 = col[e + 0];
                int j1 = col[e + 1];
                float4 v0 = *(const float4*)&Uin[(size_t)j0 * HID + foff];
                float4 v1 = *(const float4*)&Uin[(size_t)j1 * HID + foff];
                acc.x  += v0.x; acc.y  += v0.y; acc.z  += v0.z; acc.w  += v0.w;
                acc2.x += v1.x; acc2.y += v1.y; acc2.z += v1.z; acc2.w += v1.w;
            }
            if (e < e1) {
                int j = col[e];
                float4 v = *(const float4*)&Uin[(size_t)j * HID + foff];
                acc.x += v.x; acc.y += v.y; acc.z += v.z; acc.w += v.w;
            }
            float d = dis[row];
            acc.x = fmaxf(fmaf(d, acc.x + acc2.x, bb.x), 0.0f);
            acc.y = fmaxf(fmaf(d, acc.y + acc2.y, bb.y), 0.0f);
            acc.z = fmaxf(fmaf(d, acc.z + acc2.z, bb.z), 0.0f);
            acc.w = fmaxf(fmaf(d, acc.w + acc2.w, bb.w), 0.0f);
        }
        *(float4*)&S[(hw * 8 + rr) * HID + lane * 4] = acc;
    }
    // NO __syncthreads(): S rows are half-wave-private (see kernel comment).

    // ---- phase B: S @ W with register ping-pong W prefetch (round-5 body) ----
    int tx = tid & 31, ty = tid >> 5;
    int rr0 = ty * 8;
    const float4* W4 = (const float4*)W;

    float acc[8][4];
    #pragma unroll
    for (int r = 0; r < 8; ++r) { acc[r][0]=0.f; acc[r][1]=0.f; acc[r][2]=0.f; acc[r][3]=0.f; }

    float4 wa0 = W4[0 * 32 + tx];
    float4 wa1 = W4[1 * 32 + tx];
    float4 wa2 = W4[2 * 32 + tx];
    float4 wa3 = W4[3 * 32 + tx];
    float4 wb0, wb1, wb2, wb3;

    #pragma unroll 1
    for (int k = 0; k < HID; k += 8) {
        wb0 = W4[(k + 4) * 32 + tx];
        wb1 = W4[(k + 5) * 32 + tx];
        wb2 = W4[(k + 6) * 32 + tx];
        wb3 = W4[(k + 7) * 32 + tx];
        #pragma unroll
        for (int r = 0; r < 8; ++r) {
            float4 a = *(const float4*)&S[(rr0 + r) * HID + k];
            acc[r][0] = fmaf(a.x, wa0.x, acc[r][0]);
            acc[r][1] = fmaf(a.x, wa0.y, acc[r][1]);
            acc[r][2] = fmaf(a.x, wa0.z, acc[r][2]);
            acc[r][3] = fmaf(a.x, wa0.w, acc[r][3]);
            acc[r][0] = fmaf(a.y, wa1.x, acc[r][0]);
            acc[r][1] = fmaf(a.y, wa1.y, acc[r][1]);
            acc[r][2] = fmaf(a.y, wa1.z, acc[r][2]);
            acc[r][3] = fmaf(a.y, wa1.w, acc[r][3]);
            acc[r][0] = fmaf(a.z, wa2.x, acc[r][0]);
            acc[r][1] = fmaf(a.z, wa2.y, acc[r][1]);
            acc[r][2] = fmaf(a.z, wa2.z, acc[r][2]);
            acc[r][3] = fmaf(a.z, wa2.w, acc[r][3]);
            acc[r][0] = fmaf(a.w, wa3.x, acc[r][0]);
            acc[r][1] = fmaf(a.w, wa3.y, acc[r][1]);
            acc[r][2] = fmaf(a.w, wa3.z, acc[r][2]);
            acc[r][3] = fmaf(a.w, wa3.w, acc[r][3]);
        }
        if (k + 8 < HID) {
            wa0 = W4[(k + 8)  * 32 + tx];
            wa1 = W4[(k + 9)  * 32 + tx];
            wa2 = W4[(k + 10) * 32 + tx];
            wa3 = W4[(k + 11) * 32 + tx];
        }
        #pragma unroll
        for (int r = 0; r < 8; ++r) {
            float4 a = *(const float4*)&S[(rr0 + r) * HID + k + 4];
            acc[r][0] = fmaf(a.x, wb0.x, acc[r][0]);
            acc[r][1] = fmaf(a.x, wb0.y, acc[r][1]);
            acc[r][2] = fmaf(a.x, wb0.z, acc[r][2]);
            acc[r][3] = fmaf(a.x, wb0.w, acc[r][3]);
            acc[r][0] = fmaf(a.y, wb1.x, acc[r][0]);
            acc[r][1] = fmaf(a.y, wb1.y, acc[r][1]);
            acc[r][2] = fmaf(a.y, wb1.z, acc[r][2]);
            acc[r][3] = fmaf(a.y, wb1.w, acc[r][3]);
            acc[r][0] = fmaf(a.z, wb2.x, acc[r][0]);
            acc[r][1] = fmaf(a.z, wb2.y, acc[r][1]);
            acc[r][2] = fmaf(a.z, wb2.z, acc[r][2]);
            acc[r][3] = fmaf(a.z, wb2.w, acc[r][3]);
            acc[r][0] = fmaf(a.w, wb3.x, acc[r][0]);
            acc[r][1] = fmaf(a.w, wb3.y, acc[r][1]);
            acc[r][2] = fmaf(a.w, wb3.z, acc[r][2]);
            acc[r][3] = fmaf(a.w, wb3.w, acc[r][3]);
        }
    }

    int rows = n - r0; if (rows > BM) rows = BM;
    int c0 = tx * 4;
    #pragma unroll
    for (int r = 0; r < 8; ++r) {
        int row = rr0 + r;
        if (row < rows) {
            float d = dis[r0 + row];
            float4 o = make_float4(acc[r][0] * d, acc[r][1] * d, acc[r][2] * d, acc[r][3] * d);
            *(float4*)&Uout[(size_t)(r0 + row) * HID + c0] = o;
        }
    }
}

// Last layer: aggregate + bias + relu + dot with lin_w, all in registers.
// half-wave per node.
__global__ __launch_bounds__(256) void k_agglin(const float* __restrict__ Uin,
                                                const float* __restrict__ b,
                                                const float* __restrict__ dis,
                                                const int* __restrict__ rowptr,
                                                const int* __restrict__ col,
                                                const float* __restrict__ lw,
                                                const float* __restrict__ lb,
                                                float* __restrict__ out, int n) {
    int node = (blockIdx.x * 256 + threadIdx.x) >> 5;
    int lane = threadIdx.x & 31;
    if (node >= n) return;
    size_t foff = (size_t)(lane * 4);
    float4 acc = *(const float4*)&Uin[(size_t)node * HID + foff];
    float4 acc2 = make_float4(0.f, 0.f, 0.f, 0.f);
    int e = rowptr[node], e1 = rowptr[node + 1];
    for (; e + 8 <= e1; e += 8) {
        int j0 = col[e + 0];
        int j1 = col[e + 1];
        int j2 = col[e + 2];
        int j3 = col[e + 3];
        int j4 = col[e + 4];
        int j5 = col[e + 5];
        int j6 = col[e + 6];
        int j7 = col[e + 7];
        float4 v0 = *(const float4*)&Uin[(size_t)j0 * HID + foff];
        float4 v1 = *(const float4*)&Uin[(size_t)j1 * HID + foff];
        float4 v2 = *(const float4*)&Uin[(size_t)j2 * HID + foff];
        float4 v3 = *(const float4*)&Uin[(size_t)j3 * HID + foff];
        float4 v4 = *(const float4*)&Uin[(size_t)j4 * HID + foff];
        float4 v5 = *(const float4*)&Uin[(size_t)j5 * HID + foff];
        float4 v6 = *(const float4*)&Uin[(size_t)j6 * HID + foff];
        float4 v7 = *(const float4*)&Uin[(size_t)j7 * HID + foff];
        acc.x  += (v0.x + v1.x) + (v2.x + v3.x);
        acc.y  += (v0.y + v1.y) + (v2.y + v3.y);
        acc.z  += (v0.z + v1.z) + (v2.z + v3.z);
        acc.w  += (v0.w + v1.w) + (v2.w + v3.w);
        acc2.x += (v4.x + v5.x) + (v6.x + v7.x);
        acc2.y += (v4.y + v5.y) + (v6.y + v7.y);
        acc2.z += (v4.z + v5.z) + (v6.z + v7.z);
        acc2.w += (v4.w + v5.w) + (v6.w + v7.w);
    }
    for (; e + 2 <= e1; e += 2) {
        int j0 = col[e + 0];
        int j1 = col[e + 1];
        float4 v0 = *(const float4*)&Uin[(size_t)j0 * HID + foff];
        float4 v1 = *(const float4*)&Uin[(size_t)j1 * HID + foff];
        acc.x  += v0.x; acc.y  += v0.y; acc.z  += v0.z; acc.w  += v0.w;
        acc2.x += v1.x; acc2.y += v1.y; acc2.z += v1.z; acc2.w += v1.w;
    }
    if (e < e1) {
        int j = col[e];
        float4 v = *(const float4*)&Uin[(size_t)j * HID + foff];
        acc.x += v.x; acc.y += v.y; acc.z += v.z; acc.w += v.w;
    }
    float d = dis[node];
    float4 bb = *(const float4*)&b[lane * 4];
    float4 h;
    h.x = fmaxf(fmaf(d, acc.x + acc2.x, bb.x), 0.0f);
    h.y = fmaxf(fmaf(d, acc.y + acc2.y, bb.y), 0.0f);
    h.z = fmaxf(fmaf(d, acc.z + acc2.z, bb.z), 0.0f);
    h.w = fmaxf(fmaf(d, acc.w + acc2.w, bb.w), 0.0f);
    float4 ww = *(const float4*)&lw[lane * 4];
    float s = h.x * ww.x + h.y * ww.y + h.z * ww.z + h.w * ww.w;
    #pragma unroll
    for (int o = 16; o > 0; o >>= 1) s += __shfl_down(s, o, 64);  // stays within half
    if (lane == 0) out[node] = s + lb[0];
}

// ---------------- launch ----------------

extern "C" void kernel_launch(void* const* d_in, const int* in_sizes, int n_in,
                              void* d_out, int out_size, void* d_ws, size_t ws_size,
                              hipStream_t stream) {
    const float* x     = (const float*)d_in[0];
    const int*   ei    = (const int*)d_in[1];
    const float* Ws    = (const float*)d_in[2];
    const float* bs    = (const float*)d_in[3];
    const float* lin_w = (const float*)d_in[4];
    const float* lin_b = (const float*)d_in[5];
    float* out = (float*)d_out;

    int n = in_sizes[0] / HID;           // 50000
    int E = in_sizes[1] / 2;             // 600000
    int L = in_sizes[2] / (HID * HID);   // 7

    char* ws = (char*)d_ws;
    size_t off = 0;
    auto alloc = [&](size_t bytes) -> void* {
        void* p = ws + off;
        off += (bytes + 255) & ~(size_t)255;
        return p;
    };
    int*   deg     = (int*)alloc((size_t)n * 4);
    int*   cursor  = (int*)alloc((size_t)n * 4);
    int*   rowptr  = (int*)alloc((size_t)(n + 1) * 4);
    int*   partial = (int*)alloc(1024);
    float* dis     = (float*)alloc((size_t)n * 4);
    int*   col     = (int*)alloc((size_t)E * 4);
    float* ubuf0   = (float*)alloc((size_t)n * HID * 4);
    float* ubuf1   = (float*)alloc((size_t)n * HID * 4);
    (void)ws_size;

    hipMemsetAsync(deg, 0, (size_t)n * 4, stream);
    hipMemsetAsync(cursor, 0, (size_t)n * 4, stream);

    int eb = (E + 255) / 256;
    int nb = (n + 255) / 256;
    k_count<<<eb, 256, 0, stream>>>(ei, E, deg);
    k_scan1<<<nb, 256, 0, stream>>>(deg, rowptr, partial, n);
    k_scan2<<<1, 256, 0, stream>>>(partial, nb);
    k_scan3<<<nb, 256, 0, stream>>>(rowptr, partial, n, E);
    k_dis<<<nb, 256, 0, stream>>>(deg, dis, n);
    k_fill<<<eb, 256, 0, stream>>>(ei, E, rowptr, cursor, col);

    int gb = (n + BM - 1) / BM;  // 782
    int hb = (n + 7) / 8;

    // U_0 = dis * (x @ W0)
    k_gemm0<<<gb, 256, 0, stream>>>(x, Ws, dis, ubuf0, n);

    // U_{i+1} = dis * (relu(dis*agg(U_i) + b_i) @ W_{i+1})   for i = 0..L-2
    float* uin = ubuf0;
    float* uout = ubuf1;
    for (int i = 0; i + 1 < L; ++i) {
        k_aggemm<<<gb, 256, 0, stream>>>(uin, Ws + (size_t)(i + 1) * HID * HID,
                                         bs + (size_t)i * HID, dis, rowptr, col,
                                         uout, n);
        float* t = uin; uin = uout; uout = t;
    }

    // out = relu(dis*agg(U_{L-1}) + b_{L-1}) @ lin_w + lin_b
    k_agglin<<<hb, 256, 0, stream>>>(uin, bs + (size_t)(L - 1) * HID, dis,
                                     rowptr, col, lin_w, lin_b, out, n);
}